// Round 4
// baseline (410.222 us; speedup 1.0000x reference)
//
#include <hip/hip_runtime.h>
#include <hip/hip_fp16.h>

// RoI Align 14x14, bilinear, spatial_scale = 0.0625.
// features: (N=2, C=512, H=100, W=152) fp32 NCHW
// rois:     (R=512, 5) fp32
// out:      (R, 512, 14, 14) fp32
//
// v4: barrier-free wave-autonomous main kernel.
//   - NCHW fp32 -> NHWC fp16 staging (unchanged from v3b)
//   - each WAVE solo-owns (roi, 256-ch half, 98-bin half): no __syncthreads
//     in the main loop -> no vmcnt-drain, loads always in flight
//   - per bin-row (14 bins): register-prefetched taps (56x uint2),
//     wave-private LDS tile for the NCHW transpose, float2 stores
//   - refill of row r+1 issued before readback/stores of row r.

#define AH 14
#define AW 14
#define NB (AH * AW)            // 196

constexpr int Nn  = 2;
constexpr int Cc  = 512;
constexpr int Hh  = 100;
constexpr int Ww  = 152;
constexpr int HW  = Hh * Ww;    // 15200

constexpr int CHUNK = 14;       // one bin row per chunk
constexpr int TSF   = 260;      // LDS tile row stride in floats (pad: 260%32=4)

typedef float f32x4 __attribute__((ext_vector_type(4)));

// ---------------------------------------------------------------- transpose
// Per batch: A[C][HW] fp32 -> B[HW][C] fp16, 64x64 tiles via LDS.
__global__ __launch_bounds__(256)
void nchw_to_nhwc_f16(const float* __restrict__ feat, __half* __restrict__ nhwc)
{
    __shared__ float tile[64][65];

    const int n  = blockIdx.z;
    const int s0 = blockIdx.x * 64;
    const int c0 = blockIdx.y * 64;
    const int q  = (threadIdx.x & 15) * 4;   // spatial quad offset 0..60
    const int g  = threadIdx.x >> 4;         // 0..15

    const float* A = feat + (size_t)n * Cc * HW;
    __half*      B = nhwc + (size_t)n * HW * Cc;

    if (s0 + q < HW) {                        // HW % 4 == 0 -> whole quad in
        #pragma unroll
        for (int i = 0; i < 4; ++i) {
            const int cl = g + 16 * i;        // 0..63
            const f32x4 v = __builtin_nontemporal_load(
                (const f32x4*)&A[(size_t)(c0 + cl) * HW + (s0 + q)]);
            tile[cl][q + 0] = v[0];
            tile[cl][q + 1] = v[1];
            tile[cl][q + 2] = v[2];
            tile[cl][q + 3] = v[3];
        }
    }
    __syncthreads();

    const int c8    = (threadIdx.x & 7) * 8;  // channel octet 0..56
    const int sbase = threadIdx.x >> 3;       // 0..31
    #pragma unroll
    for (int i = 0; i < 2; ++i) {
        const int sl = sbase + 32 * i;        // 0..63
        if (s0 + sl < HW) {
            __half2 h[4];
            #pragma unroll
            for (int k = 0; k < 4; ++k)
                h[k] = __floats2half2_rn(tile[c8 + 2 * k][sl],
                                         tile[c8 + 2 * k + 1][sl]);
            *(uint4*)(B + (size_t)(s0 + sl) * Cc + c0 + c8) = *(uint4*)h;
        }
    }
}

// ---------------------------------------------------------------- main
__global__ __launch_bounds__(256, 2)
void roi_align_nhwc_f16(const __half* __restrict__ nhwc,
                        const float* __restrict__ rois,
                        float* __restrict__ out)
{
    const int r    = blockIdx.x;
    const int tid  = threadIdx.x;
    const int lane = tid & 63;
    const int wid  = tid >> 6;        // 0..3
    const int half = wid & 1;         // channel half (0/1)
    const int bh   = wid >> 1;        // bin half (rows 0..6 / 7..13)

    __shared__ int4   s_off[NB];              // neighbor offsets, uint2 units
    __shared__ float4 s_w[NB];
    __shared__ int    s_base;                 // batch base in halves
    __shared__ float  tiles[4][CHUNK * TSF];  // wave-private, 14.2 KB each

    const float* roi = rois + r * 5;
    const float x_start = roi[1] * 0.0625f;
    const float y_start = roi[2] * 0.0625f;
    const float roi_w = fmaxf(roi[3] * 0.0625f - x_start, 0.0f);
    const float roi_h = fmaxf(roi[4] * 0.0625f - y_start, 0.0f);
    const float bin_h = roi_h / (float)(AH - 1);
    const float bin_w = roi_w / (float)(AW - 1);

    if (tid == 0)
        s_base = ((int)roi[0]) * (HW * Cc);

    if (tid < NB) {
        const int ph = tid / AW;
        const int pw = tid - ph * AW;
        float ys = y_start + (float)ph * bin_h;
        float xs = x_start + (float)pw * bin_w;
        ys = fminf(fmaxf(ys, 0.0f), (float)(Hh - 1));
        xs = fminf(fmaxf(xs, 0.0f), (float)(Ww - 1));
        const int y0 = (int)floorf(ys);
        const int x0 = (int)floorf(xs);
        const int y1 = min(y0 + 1, Hh - 1);
        const int x1 = min(x0 + 1, Ww - 1);
        const float wy = ys - (float)y0;
        const float wx = xs - (float)x0;
        // uint2-unit offsets: pixel * (512 halves / 4 halves-per-uint2) = <<7
        s_off[tid] = make_int4((y0 * Ww + x0) << 7, (y0 * Ww + x1) << 7,
                               (y1 * Ww + x0) << 7, (y1 * Ww + x1) << 7);
        s_w[tid]   = make_float4((1.0f - wy) * (1.0f - wx),
                                 (1.0f - wy) * wx,
                                 wy * (1.0f - wx),
                                 wy * wx);
    }
    __syncthreads();   // the ONLY block-wide barrier

    // wave-solo from here on: lane = 4 channels (one uint2 per tap)
    const uint2* __restrict__ fb =
        (const uint2*)(nhwc + s_base + half * 256) + lane;
    float* __restrict__ outr = out + (size_t)r * (Cc * NB)
                             + (size_t)half * 256 * NB + bh * (7 * CHUNK);
    float* tile = tiles[wid];
    const int row0 = bh * 7;

    uint2  pf[CHUNK][4];
    float4 w_[CHUNK];

    // prologue: issue row 0's taps
    #pragma unroll
    for (int b = 0; b < CHUNK; ++b) {
        const int bin = row0 * AW + b;
        const int4 o = s_off[bin];
        w_[b] = s_w[bin];
        pf[b][0] = fb[o.x];
        pf[b][1] = fb[o.y];
        pf[b][2] = fb[o.z];
        pf[b][3] = fb[o.w];
    }

    for (int c = 0; c < 7; ++c) {
        // ---- compute row c from registers -> wave-private LDS tile
        #pragma unroll
        for (int b = 0; b < CHUNK; ++b) {
            const float4 w = w_[b];
            const uint2 A = pf[b][0], B = pf[b][1];
            const uint2 C = pf[b][2], D = pf[b][3];
            const float2 a0 = __half22float2(*(const __half2*)&A.x);
            const float2 a1 = __half22float2(*(const __half2*)&A.y);
            const float2 b0 = __half22float2(*(const __half2*)&B.x);
            const float2 b1 = __half22float2(*(const __half2*)&B.y);
            const float2 c0 = __half22float2(*(const __half2*)&C.x);
            const float2 c1 = __half22float2(*(const __half2*)&C.y);
            const float2 d0 = __half22float2(*(const __half2*)&D.x);
            const float2 d1 = __half22float2(*(const __half2*)&D.y);
            f32x4 v;
            v[0] = w.x * a0.x + w.y * b0.x + w.z * c0.x + w.w * d0.x;
            v[1] = w.x * a0.y + w.y * b0.y + w.z * c0.y + w.w * d0.y;
            v[2] = w.x * a1.x + w.y * b1.x + w.z * c1.x + w.w * d1.x;
            v[3] = w.x * a1.y + w.y * b1.y + w.z * c1.y + w.w * d1.y;
            *(f32x4*)&tile[b * TSF + lane * 4] = v;
        }

        // ---- refill: issue row c+1's taps (fly during readback/stores)
        if (c < 6) {
            #pragma unroll
            for (int b = 0; b < CHUNK; ++b) {
                const int bin = (row0 + c + 1) * AW + b;
                const int4 o = s_off[bin];
                w_[b] = s_w[bin];
                pf[b][0] = fb[o.x];
                pf[b][1] = fb[o.y];
                pf[b][2] = fb[o.z];
                pf[b][3] = fb[o.w];
            }
        }

        // ---- transposed readback + NCHW stores (wave-local sync only)
        #pragma unroll
        for (int i = 0; i < 28; ++i) {
            const int fidx = i * 64 + lane;   // 0..1791 = 256 ch * 7 f2
            const int ch   = fidx / 7;        // 0..255
            const int rem  = fidx - ch * 7;   // 0..6
            float2 v;
            v.x = tile[(rem * 2 + 0) * TSF + ch];
            v.y = tile[(rem * 2 + 1) * TSF + ch];
            *(float2*)&outr[ch * NB + c * CHUNK + rem * 2] = v;
        }
    }
}

// ---------------------------------------------------------------- fallback
// (used only if workspace is too small for the NHWC fp16 copy)
__global__ __launch_bounds__(256)
void roi_align_nchw(const float* __restrict__ feat,
                    const float* __restrict__ rois,
                    float* __restrict__ out)
{
    const int r  = blockIdx.x;
    const int c0 = blockIdx.y * 128;

    __shared__ int4   s_off[NB];
    __shared__ float4 s_w[NB];
    __shared__ int    s_base;

    const float* roi = rois + r * 5;
    const float x_start = roi[1] * 0.0625f;
    const float y_start = roi[2] * 0.0625f;
    const float roi_w = fmaxf(roi[3] * 0.0625f - x_start, 0.0f);
    const float roi_h = fmaxf(roi[4] * 0.0625f - y_start, 0.0f);
    const float bin_h = roi_h / (float)(AH - 1);
    const float bin_w = roi_w / (float)(AW - 1);

    if (threadIdx.x == 0)
        s_base = ((int)roi[0]) * (Cc * HW);

    for (int i = threadIdx.x; i < NB; i += blockDim.x) {
        const int ph = i / AW;
        const int pw = i - ph * AW;
        float ys = y_start + (float)ph * bin_h;
        float xs = x_start + (float)pw * bin_w;
        ys = fminf(fmaxf(ys, 0.0f), (float)(Hh - 1));
        xs = fminf(fmaxf(xs, 0.0f), (float)(Ww - 1));
        const int y0 = (int)floorf(ys);
        const int x0 = (int)floorf(xs);
        const int y1 = min(y0 + 1, Hh - 1);
        const int x1 = min(x0 + 1, Ww - 1);
        const float wy = ys - (float)y0;
        const float wx = xs - (float)x0;
        s_off[i] = make_int4(y0 * Ww + x0, y0 * Ww + x1,
                             y1 * Ww + x0, y1 * Ww + x1);
        s_w[i]   = make_float4((1.0f - wy) * (1.0f - wx),
                               (1.0f - wy) * wx,
                               wy * (1.0f - wx),
                               wy * wx);
    }
    __syncthreads();

    const int base = s_base;
    float* __restrict__ outr = out + (size_t)r * (Cc * NB);
    const int jend = (c0 + 128) * NB;
    for (int j = c0 * NB + (int)threadIdx.x * 4; j < jend; j += 256 * 4) {
        const int c   = j / NB;
        const int bin = j - c * NB;
        const float* f = feat + base + c * HW;
        float4 v;
        {
            const int4 o = s_off[bin];     const float4 w = s_w[bin];
            v.x = w.x*f[o.x] + w.y*f[o.y] + w.z*f[o.z] + w.w*f[o.w];
        }
        {
            const int4 o = s_off[bin + 1]; const float4 w = s_w[bin + 1];
            v.y = w.x*f[o.x] + w.y*f[o.y] + w.z*f[o.z] + w.w*f[o.w];
        }
        {
            const int4 o = s_off[bin + 2]; const float4 w = s_w[bin + 2];
            v.z = w.x*f[o.x] + w.y*f[o.y] + w.z*f[o.z] + w.w*f[o.w];
        }
        {
            const int4 o = s_off[bin + 3]; const float4 w = s_w[bin + 3];
            v.w = w.x*f[o.x] + w.y*f[o.y] + w.z*f[o.z] + w.w*f[o.w];
        }
        *(float4*)(outr + j) = v;
    }
}

extern "C" void kernel_launch(void* const* d_in, const int* in_sizes, int n_in,
                              void* d_out, int out_size, void* d_ws, size_t ws_size,
                              hipStream_t stream)
{
    const float* feat = (const float*)d_in[0];
    const float* rois = (const float*)d_in[1];
    float*       out  = (float*)d_out;
    const int R = in_sizes[1] / 5;                       // 512

    const size_t need = (size_t)Nn * HW * Cc * sizeof(__half);  // 31.1 MB
    if (ws_size >= need) {
        __half* nhwc = (__half*)d_ws;
        dim3 tg((HW + 63) / 64, Cc / 64, Nn);            // (238, 8, 2)
        nchw_to_nhwc_f16<<<tg, 256, 0, stream>>>(feat, nhwc);
        roi_align_nhwc_f16<<<dim3(R), 256, 0, stream>>>(nhwc, rois, out);
    } else {
        dim3 grid(R, Cc / 128);
        roi_align_nchw<<<grid, 256, 0, stream>>>(feat, rois, out);
    }
}

// Round 5
// 405.965 us; speedup vs baseline: 1.0105x; 1.0105x over previous
//
#include <hip/hip_runtime.h>
#include <hip/hip_fp16.h>

// RoI Align 14x14, bilinear, spatial_scale = 0.0625.
// features: (N=2, C=512, H=100, W=152) fp32 NCHW
// rois:     (R=512, 5) fp32
// out:      (R, 512, 14, 14) fp32
//
// v5: decoupled pipeline.
//   T1: NCHW fp32 -> NHWC fp16 staging (proven)
//   G : gather -> bin-major tmp[r][196][512] fp32. lane=4ch (512B coalesced
//       reads), per-bin 1KB fully-aligned contiguous wave store. No LDS tile,
//       no barriers in loop, independent bins -> deep compiler pipelining.
//   T2: per-roi 196x512 -> 512x196 transpose, 64x64 LDS tiles, coalesced
//       both sides (pure streaming, known-roofline).

#define AH 14
#define AW 14
#define NB (AH * AW)            // 196

constexpr int Nn  = 2;
constexpr int Cc  = 512;
constexpr int Hh  = 100;
constexpr int Ww  = 152;
constexpr int HW  = Hh * Ww;    // 15200

constexpr int CHUNK = 14;       // v4 fallback kernel params
constexpr int TSF   = 260;

typedef float f32x4 __attribute__((ext_vector_type(4)));

// ---------------------------------------------------------------- T1
__global__ __launch_bounds__(256)
void nchw_to_nhwc_f16(const float* __restrict__ feat, __half* __restrict__ nhwc)
{
    __shared__ float tile[64][65];

    const int n  = blockIdx.z;
    const int s0 = blockIdx.x * 64;
    const int c0 = blockIdx.y * 64;
    const int q  = (threadIdx.x & 15) * 4;
    const int g  = threadIdx.x >> 4;

    const float* A = feat + (size_t)n * Cc * HW;
    __half*      B = nhwc + (size_t)n * HW * Cc;

    if (s0 + q < HW) {
        #pragma unroll
        for (int i = 0; i < 4; ++i) {
            const int cl = g + 16 * i;
            const f32x4 v = __builtin_nontemporal_load(
                (const f32x4*)&A[(size_t)(c0 + cl) * HW + (s0 + q)]);
            tile[cl][q + 0] = v[0];
            tile[cl][q + 1] = v[1];
            tile[cl][q + 2] = v[2];
            tile[cl][q + 3] = v[3];
        }
    }
    __syncthreads();

    const int c8    = (threadIdx.x & 7) * 8;
    const int sbase = threadIdx.x >> 3;
    #pragma unroll
    for (int i = 0; i < 2; ++i) {
        const int sl = sbase + 32 * i;
        if (s0 + sl < HW) {
            __half2 h[4];
            #pragma unroll
            for (int k = 0; k < 4; ++k)
                h[k] = __floats2half2_rn(tile[c8 + 2 * k][sl],
                                         tile[c8 + 2 * k + 1][sl]);
            *(uint4*)(B + (size_t)(s0 + sl) * Cc + c0 + c8) = *(uint4*)h;
        }
    }
}

// ---------------------------------------------------------------- G
// grid (R, 2): block = roi r, channel half h (256 ch). 4 waves split bins.
__global__ __launch_bounds__(256)
void roi_gather(const __half* __restrict__ nhwc,
                const float* __restrict__ rois,
                float* __restrict__ tmp)          // [R][196][512] fp32
{
    const int r    = blockIdx.x;
    const int h    = blockIdx.y;
    const int tid  = threadIdx.x;
    const int lane = tid & 63;
    const int wid  = tid >> 6;

    __shared__ int4   s_off[NB];          // uint2-unit offsets
    __shared__ float4 s_w[NB];
    __shared__ int    s_base;

    const float* roi = rois + r * 5;
    const float x_start = roi[1] * 0.0625f;
    const float y_start = roi[2] * 0.0625f;
    const float roi_w = fmaxf(roi[3] * 0.0625f - x_start, 0.0f);
    const float roi_h = fmaxf(roi[4] * 0.0625f - y_start, 0.0f);
    const float bin_h = roi_h / (float)(AH - 1);
    const float bin_w = roi_w / (float)(AW - 1);

    if (tid == 0)
        s_base = ((int)roi[0]) * (HW * Cc);

    if (tid < NB) {
        const int ph = tid / AW;
        const int pw = tid - ph * AW;
        float ys = y_start + (float)ph * bin_h;
        float xs = x_start + (float)pw * bin_w;
        ys = fminf(fmaxf(ys, 0.0f), (float)(Hh - 1));
        xs = fminf(fmaxf(xs, 0.0f), (float)(Ww - 1));
        const int y0 = (int)floorf(ys);
        const int x0 = (int)floorf(xs);
        const int y1 = min(y0 + 1, Hh - 1);
        const int x1 = min(x0 + 1, Ww - 1);
        const float wy = ys - (float)y0;
        const float wx = xs - (float)x0;
        s_off[tid] = make_int4((y0 * Ww + x0) << 7, (y0 * Ww + x1) << 7,
                               (y1 * Ww + x0) << 7, (y1 * Ww + x1) << 7);
        s_w[tid]   = make_float4((1.0f - wy) * (1.0f - wx),
                                 (1.0f - wy) * wx,
                                 wy * (1.0f - wx),
                                 wy * wx);
    }
    __syncthreads();

    const uint2* __restrict__ fb =
        (const uint2*)(nhwc + s_base + h * 256) + lane;
    float* __restrict__ op = tmp + (size_t)r * (NB * Cc) + h * 256 + lane * 4;

    // wave wid handles bins wid, wid+4, ... (49 each); independent iterations
    #pragma unroll 4
    for (int i = 0; i < 49; ++i) {
        const int bin = wid + 4 * i;
        const int4   o = s_off[bin];
        const float4 w = s_w[bin];
        const uint2 A = fb[o.x];
        const uint2 B = fb[o.y];
        const uint2 C = fb[o.z];
        const uint2 D = fb[o.w];
        const float2 a0 = __half22float2(*(const __half2*)&A.x);
        const float2 a1 = __half22float2(*(const __half2*)&A.y);
        const float2 b0 = __half22float2(*(const __half2*)&B.x);
        const float2 b1 = __half22float2(*(const __half2*)&B.y);
        const float2 c0 = __half22float2(*(const __half2*)&C.x);
        const float2 c1 = __half22float2(*(const __half2*)&C.y);
        const float2 d0 = __half22float2(*(const __half2*)&D.x);
        const float2 d1 = __half22float2(*(const __half2*)&D.y);
        f32x4 v;
        v[0] = w.x * a0.x + w.y * b0.x + w.z * c0.x + w.w * d0.x;
        v[1] = w.x * a0.y + w.y * b0.y + w.z * c0.y + w.w * d0.y;
        v[2] = w.x * a1.x + w.y * b1.x + w.z * c1.x + w.w * d1.x;
        v[3] = w.x * a1.y + w.y * b1.y + w.z * c1.y + w.w * d1.y;
        *(f32x4*)(op + (size_t)bin * Cc) = v;   // 64 lanes x 16B = 1KB line
    }
}

// ---------------------------------------------------------------- T2
// per roi: tmp[196][512] -> out[512][196], 64x64 tiles.
__global__ __launch_bounds__(256)
void tmp_to_nchw(const float* __restrict__ tmp, float* __restrict__ out)
{
    __shared__ float tile[64][65];

    const int r  = blockIdx.z;
    const int b0 = blockIdx.x * 64;   // bin tile: 0,64,128,192
    const int c0 = blockIdx.y * 64;   // ch tile
    const int q  = (threadIdx.x & 15) * 4;
    const int g  = threadIdx.x >> 4;

    const float* A = tmp + (size_t)r * (NB * Cc);
    float*       B = out + (size_t)r * (Cc * NB);

    // read: rows = bins (512-wide), float4 along channels
    #pragma unroll
    for (int k = 0; k < 4; ++k) {
        const int bl = g + 16 * k;
        if (b0 + bl < NB) {
            const f32x4 v = *(const f32x4*)&A[(size_t)(b0 + bl) * Cc + c0 + q];
            tile[bl][q + 0] = v[0];
            tile[bl][q + 1] = v[1];
            tile[bl][q + 2] = v[2];
            tile[bl][q + 3] = v[3];
        }
    }
    __syncthreads();

    // write: rows = channels (196-wide), float4 along bins
    #pragma unroll
    for (int k = 0; k < 4; ++k) {
        const int cl = g + 16 * k;
        if (b0 + q < NB) {            // NB % 4 == 0 -> whole quad valid
            f32x4 v;
            v[0] = tile[q + 0][cl];
            v[1] = tile[q + 1][cl];
            v[2] = tile[q + 2][cl];
            v[3] = tile[q + 3][cl];
            *(f32x4*)&B[(size_t)(c0 + cl) * NB + b0 + q] = v;
        }
    }
}

// ---------------------------------------------------------------- v4 main (mid-tier fallback)
__global__ __launch_bounds__(256, 2)
void roi_align_nhwc_f16(const __half* __restrict__ nhwc,
                        const float* __restrict__ rois,
                        float* __restrict__ out)
{
    const int r    = blockIdx.x;
    const int tid  = threadIdx.x;
    const int lane = tid & 63;
    const int wid  = tid >> 6;
    const int half = wid & 1;
    const int bh   = wid >> 1;

    __shared__ int4   s_off[NB];
    __shared__ float4 s_w[NB];
    __shared__ int    s_base;
    __shared__ float  tiles[4][CHUNK * TSF];

    const float* roi = rois + r * 5;
    const float x_start = roi[1] * 0.0625f;
    const float y_start = roi[2] * 0.0625f;
    const float roi_w = fmaxf(roi[3] * 0.0625f - x_start, 0.0f);
    const float roi_h = fmaxf(roi[4] * 0.0625f - y_start, 0.0f);
    const float bin_h = roi_h / (float)(AH - 1);
    const float bin_w = roi_w / (float)(AW - 1);

    if (tid == 0)
        s_base = ((int)roi[0]) * (HW * Cc);

    if (tid < NB) {
        const int ph = tid / AW;
        const int pw = tid - ph * AW;
        float ys = y_start + (float)ph * bin_h;
        float xs = x_start + (float)pw * bin_w;
        ys = fminf(fmaxf(ys, 0.0f), (float)(Hh - 1));
        xs = fminf(fmaxf(xs, 0.0f), (float)(Ww - 1));
        const int y0 = (int)floorf(ys);
        const int x0 = (int)floorf(xs);
        const int y1 = min(y0 + 1, Hh - 1);
        const int x1 = min(x0 + 1, Ww - 1);
        const float wy = ys - (float)y0;
        const float wx = xs - (float)x0;
        s_off[tid] = make_int4((y0 * Ww + x0) << 7, (y0 * Ww + x1) << 7,
                               (y1 * Ww + x0) << 7, (y1 * Ww + x1) << 7);
        s_w[tid]   = make_float4((1.0f - wy) * (1.0f - wx),
                                 (1.0f - wy) * wx,
                                 wy * (1.0f - wx),
                                 wy * wx);
    }
    __syncthreads();

    const uint2* __restrict__ fb =
        (const uint2*)(nhwc + s_base + half * 256) + lane;
    float* __restrict__ outr = out + (size_t)r * (Cc * NB)
                             + (size_t)half * 256 * NB + bh * (7 * CHUNK);
    float* tile = tiles[wid];
    const int row0 = bh * 7;

    uint2  pf[CHUNK][4];
    float4 w_[CHUNK];

    #pragma unroll
    for (int b = 0; b < CHUNK; ++b) {
        const int bin = row0 * AW + b;
        const int4 o = s_off[bin];
        w_[b] = s_w[bin];
        pf[b][0] = fb[o.x];
        pf[b][1] = fb[o.y];
        pf[b][2] = fb[o.z];
        pf[b][3] = fb[o.w];
    }

    for (int c = 0; c < 7; ++c) {
        #pragma unroll
        for (int b = 0; b < CHUNK; ++b) {
            const float4 w = w_[b];
            const uint2 A = pf[b][0], B = pf[b][1];
            const uint2 C = pf[b][2], D = pf[b][3];
            const float2 a0 = __half22float2(*(const __half2*)&A.x);
            const float2 a1 = __half22float2(*(const __half2*)&A.y);
            const float2 b0 = __half22float2(*(const __half2*)&B.x);
            const float2 b1 = __half22float2(*(const __half2*)&B.y);
            const float2 c0 = __half22float2(*(const __half2*)&C.x);
            const float2 c1 = __half22float2(*(const __half2*)&C.y);
            const float2 d0 = __half22float2(*(const __half2*)&D.x);
            const float2 d1 = __half22float2(*(const __half2*)&D.y);
            f32x4 v;
            v[0] = w.x * a0.x + w.y * b0.x + w.z * c0.x + w.w * d0.x;
            v[1] = w.x * a0.y + w.y * b0.y + w.z * c0.y + w.w * d0.y;
            v[2] = w.x * a1.x + w.y * b1.x + w.z * c1.x + w.w * d1.x;
            v[3] = w.x * a1.y + w.y * b1.y + w.z * c1.y + w.w * d1.y;
            *(f32x4*)&tile[b * TSF + lane * 4] = v;
        }
        if (c < 6) {
            #pragma unroll
            for (int b = 0; b < CHUNK; ++b) {
                const int bin = (row0 + c + 1) * AW + b;
                const int4 o = s_off[bin];
                w_[b] = s_w[bin];
                pf[b][0] = fb[o.x];
                pf[b][1] = fb[o.y];
                pf[b][2] = fb[o.z];
                pf[b][3] = fb[o.w];
            }
        }
        #pragma unroll
        for (int i = 0; i < 28; ++i) {
            const int fidx = i * 64 + lane;
            const int ch   = fidx / 7;
            const int rem  = fidx - ch * 7;
            float2 v;
            v.x = tile[(rem * 2 + 0) * TSF + ch];
            v.y = tile[(rem * 2 + 1) * TSF + ch];
            *(float2*)&outr[ch * NB + c * CHUNK + rem * 2] = v;
        }
    }
}

// ---------------------------------------------------------------- low-tier fallback
__global__ __launch_bounds__(256)
void roi_align_nchw(const float* __restrict__ feat,
                    const float* __restrict__ rois,
                    float* __restrict__ out)
{
    const int r  = blockIdx.x;
    const int c0 = blockIdx.y * 128;

    __shared__ int4   s_off[NB];
    __shared__ float4 s_w[NB];
    __shared__ int    s_base;

    const float* roi = rois + r * 5;
    const float x_start = roi[1] * 0.0625f;
    const float y_start = roi[2] * 0.0625f;
    const float roi_w = fmaxf(roi[3] * 0.0625f - x_start, 0.0f);
    const float roi_h = fmaxf(roi[4] * 0.0625f - y_start, 0.0f);
    const float bin_h = roi_h / (float)(AH - 1);
    const float bin_w = roi_w / (float)(AW - 1);

    if (threadIdx.x == 0)
        s_base = ((int)roi[0]) * (Cc * HW);

    for (int i = threadIdx.x; i < NB; i += blockDim.x) {
        const int ph = i / AW;
        const int pw = i - ph * AW;
        float ys = y_start + (float)ph * bin_h;
        float xs = x_start + (float)pw * bin_w;
        ys = fminf(fmaxf(ys, 0.0f), (float)(Hh - 1));
        xs = fminf(fmaxf(xs, 0.0f), (float)(Ww - 1));
        const int y0 = (int)floorf(ys);
        const int x0 = (int)floorf(xs);
        const int y1 = min(y0 + 1, Hh - 1);
        const int x1 = min(x0 + 1, Ww - 1);
        const float wy = ys - (float)y0;
        const float wx = xs - (float)x0;
        s_off[i] = make_int4(y0 * Ww + x0, y0 * Ww + x1,
                             y1 * Ww + x0, y1 * Ww + x1);
        s_w[i]   = make_float4((1.0f - wy) * (1.0f - wx),
                               (1.0f - wy) * wx,
                               wy * (1.0f - wx),
                               wy * wx);
    }
    __syncthreads();

    const int base = s_base;
    float* __restrict__ outr = out + (size_t)r * (Cc * NB);
    const int jend = (c0 + 128) * NB;
    for (int j = c0 * NB + (int)threadIdx.x * 4; j < jend; j += 256 * 4) {
        const int c   = j / NB;
        const int bin = j - c * NB;
        const float* f = feat + base + c * HW;
        float4 v;
        {
            const int4 o = s_off[bin];     const float4 w = s_w[bin];
            v.x = w.x*f[o.x] + w.y*f[o.y] + w.z*f[o.z] + w.w*f[o.w];
        }
        {
            const int4 o = s_off[bin + 1]; const float4 w = s_w[bin + 1];
            v.y = w.x*f[o.x] + w.y*f[o.y] + w.z*f[o.z] + w.w*f[o.w];
        }
        {
            const int4 o = s_off[bin + 2]; const float4 w = s_w[bin + 2];
            v.z = w.x*f[o.x] + w.y*f[o.y] + w.z*f[o.z] + w.w*f[o.w];
        }
        {
            const int4 o = s_off[bin + 3]; const float4 w = s_w[bin + 3];
            v.w = w.x*f[o.x] + w.y*f[o.y] + w.z*f[o.z] + w.w*f[o.w];
        }
        *(float4*)(outr + j) = v;
    }
}

extern "C" void kernel_launch(void* const* d_in, const int* in_sizes, int n_in,
                              void* d_out, int out_size, void* d_ws, size_t ws_size,
                              hipStream_t stream)
{
    const float* feat = (const float*)d_in[0];
    const float* rois = (const float*)d_in[1];
    float*       out  = (float*)d_out;
    const int R = in_sizes[1] / 5;                       // 512

    const size_t need_nhwc = (size_t)Nn * HW * Cc * sizeof(__half); // 31.1 MB
    const size_t tmp_off   = (size_t)32 << 20;                      // 32 MB
    const size_t need_full = tmp_off + (size_t)R * NB * Cc * sizeof(float); // 237.6 MB

    if (ws_size >= need_full) {
        __half* nhwc = (__half*)d_ws;
        float*  tmp  = (float*)((char*)d_ws + tmp_off);
        dim3 tg((HW + 63) / 64, Cc / 64, Nn);            // (238, 8, 2)
        nchw_to_nhwc_f16<<<tg, 256, 0, stream>>>(feat, nhwc);
        roi_gather<<<dim3(R, 2), 256, 0, stream>>>(nhwc, rois, tmp);
        tmp_to_nchw<<<dim3(4, Cc / 64, R), 256, 0, stream>>>(tmp, out);
    } else if (ws_size >= need_nhwc) {
        __half* nhwc = (__half*)d_ws;
        dim3 tg((HW + 63) / 64, Cc / 64, Nn);
        nchw_to_nhwc_f16<<<tg, 256, 0, stream>>>(feat, nhwc);
        roi_align_nhwc_f16<<<dim3(R), 256, 0, stream>>>(nhwc, rois, out);
    } else {
        dim3 grid(R, Cc / 128);
        roi_align_nchw<<<grid, 256, 0, stream>>>(feat, rois, out);
    }
}